// Round 11
// baseline (143.998 us; speedup 1.0000x reference)
//
#include <hip/hip_runtime.h>

typedef _Float16 f16;
typedef _Float16 f16x2 __attribute__((ext_vector_type(2)));
typedef _Float16 f16x4 __attribute__((ext_vector_type(4)));
typedef _Float16 f16x8 __attribute__((ext_vector_type(8)));
typedef float    f32x4 __attribute__((ext_vector_type(4)));
typedef float    f32x16 __attribute__((ext_vector_type(16)));
typedef int      i32x4 __attribute__((ext_vector_type(4)));

#define NHEADS 16
#define DK 64
#define BATCH 2
#define SEQ 2048
#define DMODEL 1024
#define MTOT (BATCH*SEQ)          // 4096
#define NQKV (3*DMODEL)           // 3072
#define NBH  (BATCH*NHEADS)       // 32
#define LOG2E 1.44269504f
#define QSCALE (0.125f * LOG2E)   // fold 1/sqrt(dk) and log2(e) into Q
#define MASKVAL (-10000.0f * LOG2E)

__device__ inline f16x8 ld_f16x8_g(const f16* p) {
  return __builtin_bit_cast(f16x8, *reinterpret_cast<const i32x4*>(p));
}

__device__ inline f16x2 cvt_pk(float a, float b) {
  return __builtin_bit_cast(f16x2, __builtin_amdgcn_cvt_pkrtz(a, b));
}

__device__ inline void gl_lds16(const void* g, void* l) {
  __builtin_amdgcn_global_load_lds(
      (const __attribute__((address_space(1))) unsigned int*)g,
      (__attribute__((address_space(3))) unsigned int*)l, 16, 0, 0);
}

// ---------------- convert f32 -> f16, elementwise (n % 4 == 0) ----------------
__global__ void k_cvt(const float* __restrict__ in, f16* __restrict__ out, int n) {
  int i = (blockIdx.x * blockDim.x + threadIdx.x) * 4;
  if (i >= n) return;
  float4 v = *reinterpret_cast<const float4*>(in + i);
  f16x4 o = { (f16)v.x, (f16)v.y, (f16)v.z, (f16)v.w };
  *reinterpret_cast<f16x4*>(out + i) = o;
}

// ---------------- mask -> additive f32 bias in exp2 domain ----------------
__global__ void k_maskb(const int* __restrict__ mask, float* __restrict__ mb, int n) {
  int i = blockIdx.x * blockDim.x + threadIdx.x;
  if (i < n) mb[i] = mask[i] ? 0.f : MASKVAL;
}

// ------- transpose + convert: in f32 [K][N] -> out f16 [N][K] (K,N % 32 == 0) -------
__global__ void k_tcvt(const float* __restrict__ in, f16* __restrict__ out, int K, int N) {
  __shared__ float tile[32][33];
  int k0 = blockIdx.y * 32, n0 = blockIdx.x * 32;
  int tx = threadIdx.x, ty = threadIdx.y;   // block (32,8)
  #pragma unroll
  for (int i = 0; i < 4; ++i)
    tile[ty + 8*i][tx] = in[(size_t)(k0 + ty + 8*i) * N + n0 + tx];
  __syncthreads();
  #pragma unroll
  for (int i = 0; i < 4; ++i)
    out[(size_t)(n0 + ty + 8*i) * K + k0 + tx] = (f16)tile[tx][ty + 8*i];
}

// ---------------- GEMM: C[M,N] = A[M,K](f16) * Bt[N,K]^T(f16) + bias ----------------
// m97 structure: 128x128 tile, BK=64, global_load_lds width-16 staging into
// LINEAR LDS, inverse-swizzled source + XOR-swizzled fragment reads (T21).
template<int EPI>
__global__ __launch_bounds__(256, 2) void k_gemm(
    const f16* __restrict__ A, const f16* __restrict__ Bt,
    const float* __restrict__ bias,
    f16* __restrict__ qo, f16* __restrict__ ko, f16* __restrict__ vto,
    float* __restrict__ outf, int M, int N, int K)
{
  __shared__ f16 As[128][64];   // linear, 16 KB
  __shared__ f16 Bs[128][64];   // linear, 16 KB
  const int m0 = blockIdx.y * 128, n0 = blockIdx.x * 128;
  const int t = threadIdx.x;
  const int l = t & 63, w = t >> 6;
  const int wr = w >> 1, wc = w & 1;
  const int lc = l & 15, g = l >> 4;
  const int srow = l >> 3;                  // row within wave's 8-row stripe
  const int ssl  = ((l & 7) ^ srow) * 16;   // inverse-swizzled source byte slot
  const int swz  = (lc & 7) << 4;           // read-side XOR

  f32x4 acc[4][4] = {};

  for (int kt = 0; kt < K; kt += 64) {
    __syncthreads();   // previous compute done before overwriting LDS
    #pragma unroll
    for (int it = 0; it < 4; ++it) {
      int row = it*32 + w*8 + srow;          // this lane's LDS row
      gl_lds16((const char*)(A  + (size_t)(m0 + row) * K + kt) + ssl,
               &As[it*32 + w*8][0]);
      gl_lds16((const char*)(Bt + (size_t)(n0 + row) * K + kt) + ssl,
               &Bs[it*32 + w*8][0]);
    }
    __syncthreads();   // drains vmcnt (global_load_lds) + barrier

    #pragma unroll
    for (int ks = 0; ks < 64; ks += 32) {
      f16x8 af[4], bf[4];
      #pragma unroll
      for (int i = 0; i < 4; ++i) {
        const char* ab = (const char*)&As[wr*64 + i*16 + lc][0];
        af[i] = *(const f16x8*)(ab + ((ks*2 + g*16) ^ swz));
      }
      #pragma unroll
      for (int j = 0; j < 4; ++j) {
        const char* bb = (const char*)&Bs[wc*64 + j*16 + lc][0];
        bf[j] = *(const f16x8*)(bb + ((ks*2 + g*16) ^ swz));
      }
      #pragma unroll
      for (int i = 0; i < 4; ++i)
        #pragma unroll
        for (int j = 0; j < 4; ++j)
          acc[i][j] = __builtin_amdgcn_mfma_f32_16x16x32_f16(af[i], bf[j], acc[i][j], 0, 0, 0);
    }
  }

  const int lr4 = g * 4;   // C/D: row = g*4 + r, col = lc
  #pragma unroll
  for (int i = 0; i < 4; ++i) {
    #pragma unroll
    for (int j = 0; j < 4; ++j) {
      int col = n0 + wc*64 + j*16 + lc;
      float bv = bias[col];
      #pragma unroll
      for (int r = 0; r < 4; ++r) {
        int row = m0 + wr*64 + i*16 + lr4 + r;
        float v = acc[i][j][r] + bv;
        if (EPI == 0) {
          int which = col >> 10, h = (col >> 6) & 15, d = col & 63;
          int b = row >> 11, s = row & (SEQ - 1);
          size_t bh = (size_t)(b * NHEADS + h);
          if (which == 0)      qo[(bh * SEQ + s) * DK + d] = (f16)(v * QSCALE);
          else if (which == 1) ko[(bh * SEQ + s) * DK + d] = (f16)v;
          else {
            // V^T stored with sigma-permuted s within each 16-tile:
            // sigma(k) = swap bits 2 and 3 of k (involution, matches 32x32 PV B-frag)
            int sp = (s & ~12) | ((s & 4) << 1) | ((s & 8) >> 1);
            vto[(bh * DK + d) * SEQ + sp] = (f16)v;
          }
        } else {
          outf[(size_t)row * N + col] = v;
        }
      }
    }
  }
}

// ---------------- flash attention v9: 32x32 MFMA, optional cross-block split-k --
// SPLIT=1: grid 1024 = 32 bh x 16 qb x 2 ksplit, 16 k-tiles/block, 4 blocks/CU;
//          writes unnormalized O (f32) + (m,l) partials; k_merge combines.
// SPLIT=0: v8 behavior (grid 512, 32 tiles, writes ctx directly).
template<int SPLIT>
__global__ __launch_bounds__(256, 4) void k_attn9(
    const f16* __restrict__ Q, const f16* __restrict__ K,
    const f16* __restrict__ Vt, const float* __restrict__ mbias,
    f16* __restrict__ ctx, float* __restrict__ Opart, float* __restrict__ Ml)
{
  __shared__ f16 Kb[2][32][128];   // row R: k=R (128B) | k=R+32 (128B), swizzled
  __shared__ f16 Vb[2][32][128];   // row R: d=R | d=R+32

  // XCD-aware remap: bid%8 = XCD; each XCD owns 4 whole heads.
  const int bid = blockIdx.x;
  const int xcd = bid & 7, slot = bid >> 3;
  int bh, qb, ks;
  if (SPLIT) { bh = xcd*4 + (slot >> 5); qb = (slot & 31) >> 1; ks = slot & 1; }
  else       { bh = xcd*4 + (slot >> 4); qb = slot & 15;        ks = 0; }
  const int b  = bh >> 4, h = bh & (NHEADS - 1);
  const int t = threadIdx.x, l = t & 63, w = t >> 6;
  const int r31 = l & 31, hi = l >> 5;
  const int Rm = r31 & 15;
  const int q0 = qb * 128 + w * 32;
  const int kbase = SPLIT ? ks * (SEQ/2) : 0;

  const f16* Qp = Q + (size_t)bh * SEQ * DK;
  const f16* Kp = K + (size_t)bh * SEQ * DK;
  const f16* Vp = Vt + (size_t)bh * DK * SEQ;
  const float* mp = mbias + b * SEQ + kbase;

  // Q B-frags: col=q=r31, kdim d = ds*16 + hi*8 + j
  f16x8 qf[4];
  #pragma unroll
  for (int ds = 0; ds < 4; ++ds)
    qf[ds] = ld_f16x8_g(Qp + (size_t)(q0 + r31) * DK + ds*16 + hi*8);

  f32x16 o[2] = {};                 // O^T acc per d-tile (rows d, col q)
  float mrow = -3e38f;
  float lsum = 0.f;

  auto stage = [&](int buf, int kt) {
    #pragma unroll
    for (int c = 0; c < 2; ++c) {
      int Rbase = w*8 + c*4;
      int R = Rbase + (l >> 4);
      int u = (l & 15) ^ (R & 15);
      int off32 = (u >> 3) * 32;
      int byteoff = (u & 7) * 16;
      gl_lds16((const char*)Kp + (size_t)(kt + off32 + R) * (DK*2) + byteoff,
               &Kb[buf][Rbase][0]);
      gl_lds16((const char*)Vp + (size_t)(off32 + R) * (SEQ*2) + (size_t)kt*2 + byteoff,
               &Vb[buf][Rbase][0]);
    }
  };

  const int NT = SPLIT ? (SEQ/128) : (SEQ/64);
  stage(0, kbase);

  for (int it = 0; it < NT; ++it) {
    __syncthreads();                          // vmcnt(0)+lgkmcnt(0)+barrier
    if (it + 1 < NT) stage((it + 1) & 1, kbase + (it + 1) * 64);
    const int kt = it * 64;                   // offset within this split
    const char* kb = (const char*)&Kb[it & 1][0][0];
    const char* vb = (const char*)&Vb[it & 1][0][0];

    // --- bias -> QK C-init: reg r of tile T holds k=(r&3)+8*(r>>2)+4hi+32T ---
    f32x16 p[2];
    #pragma unroll
    for (int T = 0; T < 2; ++T) {
      const float* bp = mp + kt + T*32 + 4*hi;
      #pragma unroll
      for (int rq = 0; rq < 4; ++rq) {
        float4 bv = *reinterpret_cast<const float4*>(bp + rq*8);
        p[T][rq*4+0] = bv.x; p[T][rq*4+1] = bv.y;
        p[T][rq*4+2] = bv.z; p[T][rq*4+3] = bv.w;
      }
    }

    // --- S^T = K * Q^T + bias; A-frag row = k-row = r31 of tile T ---
    #pragma unroll
    for (int T = 0; T < 2; ++T)
      #pragma unroll
      for (int ds = 0; ds < 4; ++ds) {
        int slotc = T*8 + ds*2 + hi;
        f16x8 kf = *(const f16x8*)(kb + r31*256 + ((slotc ^ Rm) << 4));
        p[T] = __builtin_amdgcn_mfma_f32_32x32x16_f16(kf, qf[ds], p[T], 0, 0, 0);
      }

    // --- softmax max: pairwise tree (depth 5) then pair-lane combine ---
    float mx;
    {
      f32x4 t4;
      #pragma unroll
      for (int r = 0; r < 4; ++r)
        t4[r] = fmaxf(fmaxf(p[0][r], p[0][r+4]), fmaxf(p[0][r+8], p[0][r+12]));
      #pragma unroll
      for (int r = 0; r < 4; ++r)
        t4[r] = fmaxf(t4[r], fmaxf(fmaxf(p[1][r], p[1][r+4]), fmaxf(p[1][r+8], p[1][r+12])));
      mx = fmaxf(fmaxf(t4[0], t4[1]), fmaxf(t4[2], t4[3]));
    }
    mx = fmaxf(mx, __shfl_xor(mx, 32));

    if (!__all(mx <= mrow + 8.f)) {           // defer-max (T13), log2 domain
      float nm = fmaxf(mrow, mx);
      float sc = __builtin_amdgcn_exp2f(mrow - nm);
      mrow = nm;
      lsum *= sc;
      #pragma unroll
      for (int dt = 0; dt < 2; ++dt)
        #pragma unroll
        for (int r = 0; r < 16; ++r) o[dt][r] *= sc;
    }

    // --- P = exp2(S - m), pack pairs; partial sums for ILP ---
    f16x2 h2[2][8];
    float s0 = 0.f, s1 = 0.f;
    #pragma unroll
    for (int T = 0; T < 2; ++T)
      #pragma unroll
      for (int rp = 0; rp < 8; ++rp) {
        float e0 = __builtin_amdgcn_exp2f(p[T][2*rp]   - mrow);
        float e1 = __builtin_amdgcn_exp2f(p[T][2*rp+1] - mrow);
        s0 += e0; s1 += e1;
        h2[T][rp] = cvt_pk(e0, e1);
      }
    lsum += s0 + s1;

    // --- O^T += V^T * P : B-frag = own packed regs; kdim-16 index m = T*2+half ---
    #pragma unroll
    for (int T = 0; T < 2; ++T)
      #pragma unroll
      for (int half = 0; half < 2; ++half) {
        union { f16x2 a[4]; f16x8 v8; } pu;
        pu.a[0] = h2[T][half*4+0]; pu.a[1] = h2[T][half*4+1];
        pu.a[2] = h2[T][half*4+2]; pu.a[3] = h2[T][half*4+3];
        int m = T*2 + half;
        #pragma unroll
        for (int dt = 0; dt < 2; ++dt) {
          int slotc = dt*8 + m*2 + hi;
          f16x8 vf = *(const f16x8*)(vb + r31*256 + ((slotc ^ Rm) << 4));
          o[dt] = __builtin_amdgcn_mfma_f32_32x32x16_f16(vf, pu.v8, o[dt], 0, 0, 0);
        }
      }
  }

  // --- finalize ---
  lsum += __shfl_xor(lsum, 32);
  if (SPLIT) {
    // write unnormalized O (f32) + (m, lsum) partials
    size_t row = (size_t)bh * SEQ + q0 + r31;
    float* dst = Opart + (ks ? (size_t)NBH*SEQ*DK : 0) + row * DK;
    #pragma unroll
    for (int dt = 0; dt < 2; ++dt)
      #pragma unroll
      for (int rq = 0; rq < 4; ++rq) {
        f32x4 v4 = { o[dt][4*rq+0], o[dt][4*rq+1], o[dt][4*rq+2], o[dt][4*rq+3] };
        *(f32x4*)(dst + dt*32 + rq*8 + hi*4) = v4;
      }
    if (hi == 0) {
      float* mlp = Ml + ((ks ? (size_t)NBH*SEQ : 0) + row) * 2;
      mlp[0] = mrow;
      mlp[1] = lsum;
    }
  } else {
    float inv = 1.f / lsum;
    f16* cp = ctx + (size_t)(b*SEQ + q0 + r31) * DMODEL + h*DK;
    #pragma unroll
    for (int dt = 0; dt < 2; ++dt)
      #pragma unroll
      for (int rq = 0; rq < 4; ++rq) {
        union { f16x2 h2v[2]; f16x4 h4v; } u;
        u.h2v[0] = cvt_pk(o[dt][4*rq+0]*inv, o[dt][4*rq+1]*inv);
        u.h2v[1] = cvt_pk(o[dt][4*rq+2]*inv, o[dt][4*rq+3]*inv);
        *(f16x4*)(cp + dt*32 + 8*rq + 4*hi) = u.h4v;
      }
  }
}

// ---------------- split-k merge: combine 2 partials per q-row ----------------
// grid 16384 x 256: block = 4 rows x 64 lanes (lane = d). Fully coalesced.
__global__ __launch_bounds__(256) void k_merge(
    const float* __restrict__ Opart, const float* __restrict__ Ml,
    f16* __restrict__ ctx)
{
  const int lane = threadIdx.x & 63, sub = threadIdx.x >> 6;
  const int row = blockIdx.x * 4 + sub;          // 0..65535 = bh*SEQ + s
  const int bh = row >> 11, s = row & (SEQ - 1);
  const int b = bh >> 4, h = bh & (NHEADS - 1);
  const float* ml0 = Ml + (size_t)row * 2;
  const float* ml1 = Ml + ((size_t)NBH*SEQ + row) * 2;
  float m0 = ml0[0], l0 = ml0[1], m1 = ml1[0], l1 = ml1[1];
  float m  = fmaxf(m0, m1);
  float sa = __builtin_amdgcn_exp2f(m0 - m);
  float sb = __builtin_amdgcn_exp2f(m1 - m);
  float inv = 1.f / (l0*sa + l1*sb);
  float o0 = Opart[(size_t)row * DK + lane];
  float o1 = Opart[(size_t)NBH*SEQ*DK + (size_t)row * DK + lane];
  float v = (o0*sa + o1*sb) * inv;
  ctx[((size_t)(b*SEQ + s)) * DMODEL + h*DK + lane] = (f16)v;
}

extern "C" void kernel_launch(void* const* d_in, const int* in_sizes, int n_in,
                              void* d_out, int out_size, void* d_ws, size_t ws_size,
                              hipStream_t stream) {
  const float* x    = (const float*)d_in[0];
  const int*   mask = (const int*)d_in[1];
  const float* Wqkv = (const float*)d_in[2];
  const float* bqkv = (const float*)d_in[3];
  const float* Wout = (const float*)d_in[4];
  const float* bout = (const float*)d_in[5];
  float* out = (float*)d_out;

  const size_t SZ_X    = (size_t)MTOT * DMODEL * 2;
  const size_t SZ_WQKV = (size_t)NQKV * DMODEL * 2;
  const size_t SZ_WOUT = (size_t)DMODEL * DMODEL * 2;
  const size_t SZ_QKV  = (size_t)BATCH * NHEADS * SEQ * DK * 2;
  const size_t SZ_MB   = (size_t)MTOT * 4;               // 4096 floats = 16 KB (was /2: BUG)
  const size_t SZ_OP   = (size_t)2 * NBH * SEQ * DK * 4; // 33.5 MB
  const size_t SZ_ML   = (size_t)2 * NBH * SEQ * 2 * 4;  // 2 MB
  const size_t NEED_BASE  = SZ_X + SZ_WQKV + SZ_WOUT + 3*SZ_QKV + SZ_X + SZ_MB;
  const size_t NEED_SPLIT = NEED_BASE + SZ_OP + SZ_ML;
  if (ws_size < NEED_BASE) return;
  const bool use_split = (ws_size >= NEED_SPLIT);

  char* p = (char*)d_ws;
  f16* xh    = (f16*)p; p += SZ_X;
  f16* Wqkvt = (f16*)p; p += SZ_WQKV;
  f16* Woutt = (f16*)p; p += SZ_WOUT;
  f16* Qh    = (f16*)p; p += SZ_QKV;
  f16* Kh    = (f16*)p; p += SZ_QKV;
  f16* Vth   = (f16*)p; p += SZ_QKV;
  f16* ctx   = (f16*)p; p += SZ_X;
  float* mb  = (float*)p; p += SZ_MB;
  float* Opart = (float*)p; p += SZ_OP;
  float* Ml    = (float*)p; p += SZ_ML;

  k_cvt<<<(MTOT*DMODEL)/(256*4), 256, 0, stream>>>(x, xh, MTOT*DMODEL);
  k_maskb<<<(BATCH*SEQ + 255)/256, 256, 0, stream>>>(mask, mb, BATCH*SEQ);
  k_tcvt<<<dim3(NQKV/32, DMODEL/32), dim3(32,8), 0, stream>>>(Wqkv, Wqkvt, DMODEL, NQKV);
  k_tcvt<<<dim3(DMODEL/32, DMODEL/32), dim3(32,8), 0, stream>>>(Wout, Woutt, DMODEL, DMODEL);

  k_gemm<0><<<dim3(NQKV/128, MTOT/128), 256, 0, stream>>>(
      xh, Wqkvt, bqkv, Qh, Kh, Vth, nullptr, MTOT, NQKV, DMODEL);

  if (use_split) {
    k_attn9<1><<<32 * 16 * 2, 256, 0, stream>>>(Qh, Kh, Vth, mb, ctx, Opart, Ml);
    k_merge<<<(NBH*SEQ)/4, 256, 0, stream>>>(Opart, Ml, ctx);
  } else {
    k_attn9<0><<<32 * 16, 256, 0, stream>>>(Qh, Kh, Vth, mb, ctx, Opart, Ml);
  }

  k_gemm<1><<<dim3(DMODEL/128, MTOT/128), 256, 0, stream>>>(
      ctx, Woutt, bout, nullptr, nullptr, nullptr, out, MTOT, DMODEL, DMODEL);
}